// Round 14
// baseline (2483.075 us; speedup 1.0000x reference)
//
#include <hip/hip_runtime.h>
#include <hip/hip_bf16.h>
#include <stdint.h>

// SimpleRNN: B=64, S=512, H=1024, V=128
// Phase 1: persistent 32-wg recurrence, 32 cols of W_hh per wg (LDS, 64 KB).
//   R8-proven protocol (wg flags in d_ws, syncthreads-drain arrival, bounded
//   spins, sc1/L3 exchange, triple-buffered h in MFMA A-frag layout).
//   NEW vs R13: per-PRODUCER software pipeline — wave ki consumes producer
//   j's 2 fragments (kst=2j,2j+1) as soon as flag j lands: poll(j+1) ->
//   load(j+1) -> vmcnt(2) -> mfma(j). Accumulation order unchanged (bitwise
//   identical to R13).
// Phase 2: logits GEMM (hidden bf16 @ W_out bf16, 32x32x16 MFMA) + b_out

#define Bz 64
#define Sz 512
#define Hz 1024
#define Vz 128
#define NWG 32
#define COLS 32   // Hz / NWG columns of W_hh per workgroup
#define WGT 512   // threads per wg (8 waves): 2 M-tiles x 4 K-splits

typedef __attribute__((ext_vector_type(8)))  short short8;
typedef __attribute__((ext_vector_type(16))) float f32x16;
typedef __attribute__((ext_vector_type(4)))  unsigned u32x4;   // asm-friendly 16B
typedef __attribute__((ext_vector_type(2)))  unsigned u32x2;   // asm-friendly 8B

// h TRIPLE buffer in MFMA A-fragment order:
// g_hfrag[gen][mi=m>>5][kb=k>>4][lane=((k>>3)&1)*32+(m&31)][j=k&7]
__device__ __align__(16) unsigned short g_hfrag[3][2][64][64][8];   // 3 x 128 KB
// hidden states, fragment order per step: [s][mi][kb][lane][8]  (64 MB)
__device__ __align__(16) unsigned short g_hidden[(size_t)Sz*2*64*64*8];
// W_out packed for 32x32x16 B-frags: [kb][nt][lane][8]  (256 KB)
__device__ __align__(16) unsigned short g_wout[64*4*64*8];

__device__ __forceinline__ unsigned short f2bf(float f) {
  union { float f; unsigned u; } v; v.f = f;
  unsigned r = v.u + 0x7FFFu + ((v.u >> 16) & 1u);      // RNE
  return (unsigned short)(r >> 16);
}

__device__ __forceinline__ float fast_tanh(float x) {
  float cx = fminf(9.0f, fmaxf(-9.0f, x));
  float e  = __builtin_amdgcn_exp2f(cx * 2.88539008178f);   // e^(2x)
  return (e - 1.0f) * __builtin_amdgcn_rcpf(e + 1.0f);
}

// 2 coherent (sc1 -> L3) 16-B loads, NO internal drain (pipeline stage issue).
// Each instruction is a fully-coalesced 1 KB wave read (lane stride 16 B).
__device__ __forceinline__ void load2_sc1(const unsigned short* p,
                                          u32x4& t0, u32x4& t1) {
  asm volatile(
    "global_load_dwordx4 %0, %2, off sc1\n\t"
    "global_load_dwordx4 %1, %2, off offset:1024 sc1"
    : "=&v"(t0), "=&v"(t1)
    : "v"(p)
    : "memory");
}
// vmcnt fences tied to the fragment registers they guard (data-dep ordering).
__device__ __forceinline__ void waitv2(u32x4& a, u32x4& b) {
  asm volatile("s_waitcnt vmcnt(2)" : "+v"(a), "+v"(b));
}
__device__ __forceinline__ void waitv0(u32x4& a, u32x4& b) {
  asm volatile("s_waitcnt vmcnt(0)" : "+v"(a), "+v"(b));
}

// agent-scope write-through stores (visible at L3 once vmcnt retires)
__device__ __forceinline__ void store16_sc1(unsigned short* p, u32x4 v) {
  asm volatile("global_store_dwordx4 %0, %1, off sc1" :: "v"(p), "v"(v) : "memory");
}
__device__ __forceinline__ void store8_sc1(unsigned short* p, u32x2 v) {
  asm volatile("global_store_dwordx2 %0, %1, off sc1" :: "v"(p), "v"(v) : "memory");
}

// ---- Phase 0: pack W_out (H,V) fp32 -> [kb][nt][lane][8] bf16 (32x32 B-frag) --
__global__ void pack_wout(const float* __restrict__ W_out) {
  int gid = blockIdx.x * blockDim.x + threadIdx.x;      // 0..16383
  int lane = gid & 63;
  int nt   = (gid >> 6) & 3;
  int kb   = gid >> 8;
  int n = nt * 32 + (lane & 31);
  int k0 = kb * 16 + (lane >> 5) * 8;
  unsigned short t[8];
#pragma unroll
  for (int j = 0; j < 8; ++j)
    t[j] = f2bf(W_out[(size_t)(k0 + j) * Vz + n]);
  uint4 w;
  w.x = (unsigned)t[0] | ((unsigned)t[1] << 16);
  w.y = (unsigned)t[2] | ((unsigned)t[3] << 16);
  w.z = (unsigned)t[4] | ((unsigned)t[5] << 16);
  w.w = (unsigned)t[6] | ((unsigned)t[7] << 16);
  *(uint4*)&g_wout[(size_t)gid * 8] = w;
}

// ---------------- Phase 1: persistent recurrence -----------------------------
__global__ __launch_bounds__(WGT) void rnn_persistent(
    const int* __restrict__ x, const float* __restrict__ h0,
    const float* __restrict__ W_xh, const float* __restrict__ W_hh,
    const float* __restrict__ b_h, float* __restrict__ out,
    unsigned* __restrict__ flags)
{
  // W slice (32 cols): fragment layout [kb8][n32][j] -> ds_read_b128
  __shared__ unsigned short ldsW[128 * 32 * 8];         // 64 KB
  // 4 K-split partial regions, XOR-swizzled: red[ki*2048 + m*32 + (c^(m&31))]
  __shared__ float red[4 * 64 * 32];                    // 32 KB
  // 96 KB total -> at most 1 wg per CU (forces spreading of all 32 wgs)

  const int g    = blockIdx.x;        // 0..31
  const int n0g  = g * COLS;          // global column base of this wg's W slice
  const int tid  = threadIdx.x;
  const int lane = tid & 63;
  const int wv   = tid >> 6;          // 0..7
  const int mi   = wv & 1;            // M-tile (32 rows)
  const int ki   = wv >> 1;           // K-split (256 each)
  const int bn   = lane & 31;

  // ---- stage W_hh[:, n0g : n0g+32) -> ldsW (one-time) ----
  for (int idx = tid; idx < 128 * 32; idx += WGT) {
    int kb = idx >> 5, n = idx & 31;
    unsigned short t[8];
#pragma unroll
    for (int j = 0; j < 8; ++j)
      t[j] = f2bf(W_hh[(size_t)(kb * 8 + j) * Hz + n0g + n]);
    uint4 w;
    w.x = (unsigned)t[0] | ((unsigned)t[1] << 16);
    w.y = (unsigned)t[2] | ((unsigned)t[3] << 16);
    w.z = (unsigned)t[4] | ((unsigned)t[5] << 16);
    w.w = (unsigned)t[6] | ((unsigned)t[7] << 16);
    *(uint4*)&ldsW[(size_t)idx * 8] = w;
  }

  // ---- h0 -> g_hfrag[0]; wg g stages slots [g*256, g*256+256) ----
  if (tid < 256) {
    int s_idx = g * 256 + tid;              // 0..8191 over all wgs
    int fmi = s_idx >> 12, fkb = (s_idx >> 6) & 63, fL = s_idx & 63;
    int m = fmi * 32 + (fL & 31);
    int k = fkb * 16 + (fL >> 5) * 8;
    const float* src = &h0[(size_t)m * Hz + k];
    float4 a0 = *(const float4*)&src[0];
    float4 a1 = *(const float4*)&src[4];
    u32x4 w;
    w.x = (unsigned)f2bf(a0.x) | ((unsigned)f2bf(a0.y) << 16);
    w.y = (unsigned)f2bf(a0.z) | ((unsigned)f2bf(a0.w) << 16);
    w.z = (unsigned)f2bf(a1.x) | ((unsigned)f2bf(a1.y) << 16);
    w.w = (unsigned)f2bf(a1.z) | ((unsigned)f2bf(a1.w) << 16);
    store16_sc1(&g_hfrag[0][fmi][fkb][fL][0], w);
  }

  // ---- initial FULL barrier (R8 form): h0 + W staged everywhere ----
  {
    __syncthreads();
    if (tid == 0)
      __hip_atomic_store(&flags[g * 8], 1u, __ATOMIC_RELAXED,
                         __HIP_MEMORY_SCOPE_AGENT);
    if (wv == 0) {
      for (int it = 0; it < 65536; ++it) {
        unsigned v = 0xFFFFFFFFu;
        if (lane < NWG)
          v = __hip_atomic_load(&flags[lane * 8], __ATOMIC_RELAXED,
                                __HIP_MEMORY_SCOPE_AGENT);
        if (__all(v >= 1u)) break;
        __builtin_amdgcn_s_sleep(1);
      }
    }
    __syncthreads();
    asm volatile("" ::: "memory");
  }

  // wave-uniform poll of one producer flag (bounded; all lanes same address)
  auto pollflag = [&](int gp, unsigned tgt) {
    const unsigned* fp = &flags[gp * 8];
    for (int it = 0; it < 65536; ++it) {
      if (__hip_atomic_load(fp, __ATOMIC_RELAXED,
                            __HIP_MEMORY_SCOPE_AGENT) >= tgt) break;
      __builtin_amdgcn_s_sleep(1);
    }
    asm volatile("" ::: "memory");
  };

  // epilogue mapping: em = (lane&31)+32*(wv&1) (row), 4 cols at c0
  const int em   = (lane & 31) + 32 * (wv & 1);
  const int c0   = ((wv >> 1) * 2 + (lane >> 5)) * 4;
  const int kcol = n0g + c0;
  const int kb_g = kcol >> 4;                 // global kb plane (2g or 2g+1)
  const int kq   = (c0 >> 3) & 1;
  const int lslot = kq * 32 + (em & 31);
  const size_t slotOff =
      ((((size_t)(wv & 1) * 64 + kb_g) * 64) + lslot) * 8 + (c0 & 7);
  float bias[4];
#pragma unroll
  for (int j = 0; j < 4; ++j) bias[j] = b_h[kcol + j];

  // prefetch step-0 token + embedding row
  int tok_n = x[em * Sz];
  float4 xv_n = *(const float4*)&W_xh[(size_t)tok_n * Hz + kcol];

  int rp = 0;                               // read generation = s % 3
  for (int s = 0; s < Sz; ++s) {
    const int wp = (rp == 2) ? 0 : rp + 1;  // write generation
    const unsigned tgt = (unsigned)(s + 1); // producers' step-s data flag

    // ---- per-producer pipelined wait+load+MFMA ----
    // producer j = wg 8ki+j owns kst = 2j, 2j+1 (kb planes ki*16+2j, +1).
    const unsigned short* pb = &g_hfrag[rp][mi][ki * 16][lane][0];
    u32x4 t[16];
    f32x16 acc = {};
    pollflag(8 * ki + 0, tgt);
    load2_sc1(pb, t[0], t[1]);
#pragma unroll
    for (int j = 0; j < 7; ++j) {
      pollflag(8 * ki + j + 1, tgt);
      load2_sc1(pb + (size_t)(j + 1) * 1024, t[2 * j + 2], t[2 * j + 3]);
      waitv2(t[2 * j], t[2 * j + 1]);
      {
        int kb8a = ki * 32 + (2 * j) * 2 + (lane >> 5);
        int kb8b = ki * 32 + (2 * j + 1) * 2 + (lane >> 5);
        short8 ba = *(const short8*)&ldsW[(size_t)(kb8a * 32 + bn) * 8];
        short8 bb = *(const short8*)&ldsW[(size_t)(kb8b * 32 + bn) * 8];
        acc = __builtin_amdgcn_mfma_f32_32x32x16_bf16(*(short8*)&t[2 * j],     ba, acc, 0, 0, 0);
        acc = __builtin_amdgcn_mfma_f32_32x32x16_bf16(*(short8*)&t[2 * j + 1], bb, acc, 0, 0, 0);
      }
    }
    waitv0(t[14], t[15]);
    {
      int kb8a = ki * 32 + 14 * 2 + (lane >> 5);
      int kb8b = ki * 32 + 15 * 2 + (lane >> 5);
      short8 ba = *(const short8*)&ldsW[(size_t)(kb8a * 32 + bn) * 8];
      short8 bb = *(const short8*)&ldsW[(size_t)(kb8b * 32 + bn) * 8];
      acc = __builtin_amdgcn_mfma_f32_32x32x16_bf16(*(short8*)&t[14], ba, acc, 0, 0, 0);
      acc = __builtin_amdgcn_mfma_f32_32x32x16_bf16(*(short8*)&t[15], bb, acc, 0, 0, 0);
    }

    // prefetch NEXT step's token + embedding row (hides gather latency)
    float4 xv = xv_n;
    if (s + 1 < Sz) {
      int t2 = x[em * Sz + s + 1];
      xv_n = *(const float4*)&W_xh[(size_t)t2 * Hz + kcol];
    }

    // single-sync 4-region K-split reduction (XOR-swizzled, <=2-way banks)
    // C/D: col=lane&31, row=(reg&3)+8*(reg>>2)+4*(lane>>5)  [m74/m101]
    {
      const int crow = 4 * (lane >> 5);
      float* reg = &red[ki * 2048];
#pragma unroll
      for (int r = 0; r < 16; ++r) {
        int m = mi * 32 + crow + (r & 3) + 8 * (r >> 2);
        reg[m * 32 + (bn ^ (m & 31))] = acc[r];
      }
    }
    __syncthreads();

    // epilogue: z = sum of 4 partials + emb + bias; h = tanh(z)
    float z[4];
    {
      const int sw = em & 31;
      const int base = em * 32;
#pragma unroll
      for (int j = 0; j < 4; ++j) {
        int off = base + ((c0 + j) ^ sw);
        z[j] = (red[off] + red[2048 + off]) + (red[4096 + off] + red[6144 + off]);
      }
    }
    z[0] = fast_tanh(z[0] + xv.x + bias[0]);
    z[1] = fast_tanh(z[1] + xv.y + bias[1]);
    z[2] = fast_tanh(z[2] + xv.z + bias[2]);
    z[3] = fast_tanh(z[3] + xv.w + bias[3]);

    u32x2 w2;
    w2.x = (unsigned)f2bf(z[0]) | ((unsigned)f2bf(z[1]) << 16);
    w2.y = (unsigned)f2bf(z[2]) | ((unsigned)f2bf(z[3]) << 16);

    // h store: fragment layout, wave-coalesced, write-through to L3
    store8_sc1(&((unsigned short*)g_hfrag)[(size_t)wp * 65536 + slotOff], w2);

    if (s == Sz - 1) {
      *(u32x2*)&g_hidden[(size_t)s * 65536 + slotOff] = w2;
      float* hf = out + (size_t)Bz * Sz * Vz + (size_t)em * Hz + kcol;
      float4 f0 = {z[0], z[1], z[2], z[3]};
      *(float4*)hf = f0;
    } else {
      // arrival (R8-proven): syncthreads drains all waves' h stores, then
      // tid0 publishes the wg flag. Consumer waits happen at next loop top.
      __syncthreads();
      if (tid == 0)
        __hip_atomic_store(&flags[g * 8], (unsigned)(s + 2), __ATOMIC_RELAXED,
                           __HIP_MEMORY_SCOPE_AGENT);
      // overlapped with flag propagation:
      *(u32x2*)&g_hidden[(size_t)s * 65536 + slotOff] = w2;
      asm volatile("" ::: "memory");
    }
    rp = wp;
  }
}

// ---------------- Phase 2: logits = hidden @ W_out + b_out -------------------
// grid: 1024 blocks = (s, mi); 4 waves; wave nt computes 32 rows x 32 cols, K=1024
__global__ __launch_bounds__(256) void logits_gemm(
    const float* __restrict__ b_out, float* __restrict__ out)
{
  const int tid = threadIdx.x, lane = tid & 63, nt = tid >> 6;
  const int s = blockIdx.x >> 1, mi = blockIdx.x & 1;
  const unsigned short* ab = &g_hidden[((size_t)s * 8192 + (size_t)mi * 4096) * 8];

  f32x16 acc = {};
#pragma unroll 8
  for (int kb = 0; kb < 64; ++kb) {
    short8 a = *(const short8*)&ab[(size_t)(kb * 64 + lane) * 8];
    short8 b = *(const short8*)&g_wout[(size_t)((kb * 4 + nt) * 64 + lane) * 8];
    acc = __builtin_amdgcn_mfma_f32_32x32x16_bf16(a, b, acc, 0, 0, 0);
  }
  const int col = nt * 32 + (lane & 31);
  const float bo = b_out[col];
  const int rbase = 4 * (lane >> 5);
#pragma unroll
  for (int r = 0; r < 16; ++r) {
    int m = rbase + (r & 3) + 8 * (r >> 2);
    int em = mi * 32 + m;
    out[((size_t)em * Sz + s) * Vz + col] = acc[r] + bo;
  }
}

// ---------------- host launcher ----------------------------------------------
extern "C" void kernel_launch(void* const* d_in, const int* in_sizes, int n_in,
                              void* d_out, int out_size, void* d_ws, size_t ws_size,
                              hipStream_t stream) {
  const int*   x     = (const int*)d_in[0];
  const float* h0    = (const float*)d_in[1];
  const float* W_xh  = (const float*)d_in[2];
  const float* W_hh  = (const float*)d_in[3];
  const float* b_h   = (const float*)d_in[4];
  const float* W_out = (const float*)d_in[5];
  const float* b_out = (const float*)d_in[6];
  float* out = (float*)d_out;

  (void)hipMemsetAsync(d_ws, 0, 1024, stream);    // 32 wg-flag lines (32 B each)
  pack_wout<<<64, 256, 0, stream>>>(W_out);
  rnn_persistent<<<NWG, WGT, 0, stream>>>(x, h0, W_xh, W_hh, b_h, out,
                                          (unsigned*)d_ws);
  logits_gemm<<<Sz * 2, 256, 0, stream>>>(b_out, out);
}

// Round 15
// 1596.402 us; speedup vs baseline: 1.5554x; 1.5554x over previous
//
#include <hip/hip_runtime.h>
#include <hip/hip_bf16.h>
#include <stdint.h>

// SimpleRNN: B=64, S=512, H=1024, V=128
// Phase 1: persistent 32-wg recurrence, 32 cols of W_hh per wg (LDS, 64 KB).
//   R13-proven protocol: wg flags in d_ws, syncthreads-drain arrival, ONE
//   parallel 8-lane producer poll per step, bounded spins, sc1/L3 exchange,
//   triple-buffered h in MFMA A-frag layout.
//   NEW vs R13: fragment loads issued WITHOUT drain, consumed in pairs gated
//   by descending s_waitcnt vmcnt(14..0) with MFMAs interleaved (overlaps L3
//   transfer with compute). Accumulation order unchanged.
// Phase 2: logits GEMM (hidden bf16 @ W_out bf16, 32x32x16 MFMA) + b_out

#define Bz 64
#define Sz 512
#define Hz 1024
#define Vz 128
#define NWG 32
#define COLS 32   // Hz / NWG columns of W_hh per workgroup
#define WGT 512   // threads per wg (8 waves): 2 M-tiles x 4 K-splits

typedef __attribute__((ext_vector_type(8)))  short short8;
typedef __attribute__((ext_vector_type(16))) float f32x16;
typedef __attribute__((ext_vector_type(4)))  unsigned u32x4;   // asm-friendly 16B
typedef __attribute__((ext_vector_type(2)))  unsigned u32x2;   // asm-friendly 8B

// h TRIPLE buffer in MFMA A-fragment order:
// g_hfrag[gen][mi=m>>5][kb=k>>4][lane=((k>>3)&1)*32+(m&31)][j=k&7]
__device__ __align__(16) unsigned short g_hfrag[3][2][64][64][8];   // 3 x 128 KB
// hidden states, fragment order per step: [s][mi][kb][lane][8]  (64 MB)
__device__ __align__(16) unsigned short g_hidden[(size_t)Sz*2*64*64*8];
// W_out packed for 32x32x16 B-frags: [kb][nt][lane][8]  (256 KB)
__device__ __align__(16) unsigned short g_wout[64*4*64*8];

__device__ __forceinline__ unsigned short f2bf(float f) {
  union { float f; unsigned u; } v; v.f = f;
  unsigned r = v.u + 0x7FFFu + ((v.u >> 16) & 1u);      // RNE
  return (unsigned short)(r >> 16);
}

__device__ __forceinline__ float fast_tanh(float x) {
  float cx = fminf(9.0f, fmaxf(-9.0f, x));
  float e  = __builtin_amdgcn_exp2f(cx * 2.88539008178f);   // e^(2x)
  return (e - 1.0f) * __builtin_amdgcn_rcpf(e + 1.0f);
}

// 16 coherent (sc1 -> L3) 16-B loads, NO drain — pipeline issue stage.
// Each instruction is a fully-coalesced 1 KB wave read (lane stride 16 B).
__device__ __forceinline__ void load16_nodrain(const unsigned short* p0, u32x4 t[16]) {
  const unsigned short* p1 = p0 + 2048;   // +4096 B
  const unsigned short* p2 = p0 + 4096;   // +8192 B
  const unsigned short* p3 = p0 + 6144;   // +12288 B
  asm volatile(
    "global_load_dwordx4 %0,  %16, off sc1\n\t"
    "global_load_dwordx4 %1,  %16, off offset:1024 sc1\n\t"
    "global_load_dwordx4 %2,  %16, off offset:2048 sc1\n\t"
    "global_load_dwordx4 %3,  %16, off offset:3072 sc1\n\t"
    "global_load_dwordx4 %4,  %17, off sc1\n\t"
    "global_load_dwordx4 %5,  %17, off offset:1024 sc1\n\t"
    "global_load_dwordx4 %6,  %17, off offset:2048 sc1\n\t"
    "global_load_dwordx4 %7,  %17, off offset:3072 sc1\n\t"
    "global_load_dwordx4 %8,  %18, off sc1\n\t"
    "global_load_dwordx4 %9,  %18, off offset:1024 sc1\n\t"
    "global_load_dwordx4 %10, %18, off offset:2048 sc1\n\t"
    "global_load_dwordx4 %11, %18, off offset:3072 sc1\n\t"
    "global_load_dwordx4 %12, %19, off sc1\n\t"
    "global_load_dwordx4 %13, %19, off offset:1024 sc1\n\t"
    "global_load_dwordx4 %14, %19, off offset:2048 sc1\n\t"
    "global_load_dwordx4 %15, %19, off offset:3072 sc1"
    : "=&v"(t[0]), "=&v"(t[1]), "=&v"(t[2]),  "=&v"(t[3]),
      "=&v"(t[4]), "=&v"(t[5]), "=&v"(t[6]),  "=&v"(t[7]),
      "=&v"(t[8]), "=&v"(t[9]), "=&v"(t[10]), "=&v"(t[11]),
      "=&v"(t[12]),"=&v"(t[13]),"=&v"(t[14]), "=&v"(t[15])
    : "v"(p0), "v"(p1), "v"(p2), "v"(p3)
    : "memory");
}

// agent-scope write-through stores (visible at L3 once vmcnt retires)
__device__ __forceinline__ void store16_sc1(unsigned short* p, u32x4 v) {
  asm volatile("global_store_dwordx4 %0, %1, off sc1" :: "v"(p), "v"(v) : "memory");
}
__device__ __forceinline__ void store8_sc1(unsigned short* p, u32x2 v) {
  asm volatile("global_store_dwordx2 %0, %1, off sc1" :: "v"(p), "v"(v) : "memory");
}

// ---- Phase 0: pack W_out (H,V) fp32 -> [kb][nt][lane][8] bf16 (32x32 B-frag) --
__global__ void pack_wout(const float* __restrict__ W_out) {
  int gid = blockIdx.x * blockDim.x + threadIdx.x;      // 0..16383
  int lane = gid & 63;
  int nt   = (gid >> 6) & 3;
  int kb   = gid >> 8;
  int n = nt * 32 + (lane & 31);
  int k0 = kb * 16 + (lane >> 5) * 8;
  unsigned short t[8];
#pragma unroll
  for (int j = 0; j < 8; ++j)
    t[j] = f2bf(W_out[(size_t)(k0 + j) * Vz + n]);
  uint4 w;
  w.x = (unsigned)t[0] | ((unsigned)t[1] << 16);
  w.y = (unsigned)t[2] | ((unsigned)t[3] << 16);
  w.z = (unsigned)t[4] | ((unsigned)t[5] << 16);
  w.w = (unsigned)t[6] | ((unsigned)t[7] << 16);
  *(uint4*)&g_wout[(size_t)gid * 8] = w;
}

// ---------------- Phase 1: persistent recurrence -----------------------------
__global__ __launch_bounds__(WGT) void rnn_persistent(
    const int* __restrict__ x, const float* __restrict__ h0,
    const float* __restrict__ W_xh, const float* __restrict__ W_hh,
    const float* __restrict__ b_h, float* __restrict__ out,
    unsigned* __restrict__ flags)
{
  // W slice (32 cols): fragment layout [kb8][n32][j] -> ds_read_b128
  __shared__ unsigned short ldsW[128 * 32 * 8];         // 64 KB
  // 4 K-split partial regions, XOR-swizzled: red[ki*2048 + m*32 + (c^(m&31))]
  __shared__ float red[4 * 64 * 32];                    // 32 KB
  // 96 KB total -> at most 1 wg per CU (forces spreading of all 32 wgs)

  const int g    = blockIdx.x;        // 0..31
  const int n0g  = g * COLS;          // global column base of this wg's W slice
  const int tid  = threadIdx.x;
  const int lane = tid & 63;
  const int wv   = tid >> 6;          // 0..7
  const int mi   = wv & 1;            // M-tile (32 rows)
  const int ki   = wv >> 1;           // K-split (256 each)
  const int bn   = lane & 31;

  // ---- stage W_hh[:, n0g : n0g+32) -> ldsW (one-time) ----
  for (int idx = tid; idx < 128 * 32; idx += WGT) {
    int kb = idx >> 5, n = idx & 31;
    unsigned short t[8];
#pragma unroll
    for (int j = 0; j < 8; ++j)
      t[j] = f2bf(W_hh[(size_t)(kb * 8 + j) * Hz + n0g + n]);
    uint4 w;
    w.x = (unsigned)t[0] | ((unsigned)t[1] << 16);
    w.y = (unsigned)t[2] | ((unsigned)t[3] << 16);
    w.z = (unsigned)t[4] | ((unsigned)t[5] << 16);
    w.w = (unsigned)t[6] | ((unsigned)t[7] << 16);
    *(uint4*)&ldsW[(size_t)idx * 8] = w;
  }

  // ---- h0 -> g_hfrag[0]; wg g stages slots [g*256, g*256+256) ----
  if (tid < 256) {
    int s_idx = g * 256 + tid;              // 0..8191 over all wgs
    int fmi = s_idx >> 12, fkb = (s_idx >> 6) & 63, fL = s_idx & 63;
    int m = fmi * 32 + (fL & 31);
    int k = fkb * 16 + (fL >> 5) * 8;
    const float* src = &h0[(size_t)m * Hz + k];
    float4 a0 = *(const float4*)&src[0];
    float4 a1 = *(const float4*)&src[4];
    u32x4 w;
    w.x = (unsigned)f2bf(a0.x) | ((unsigned)f2bf(a0.y) << 16);
    w.y = (unsigned)f2bf(a0.z) | ((unsigned)f2bf(a0.w) << 16);
    w.z = (unsigned)f2bf(a1.x) | ((unsigned)f2bf(a1.y) << 16);
    w.w = (unsigned)f2bf(a1.z) | ((unsigned)f2bf(a1.w) << 16);
    store16_sc1(&g_hfrag[0][fmi][fkb][fL][0], w);
  }

  // ---- initial FULL barrier (R8 form): h0 + W staged everywhere ----
  {
    __syncthreads();
    if (tid == 0)
      __hip_atomic_store(&flags[g * 8], 1u, __ATOMIC_RELAXED,
                         __HIP_MEMORY_SCOPE_AGENT);
    if (wv == 0) {
      for (int it = 0; it < 65536; ++it) {
        unsigned v = 0xFFFFFFFFu;
        if (lane < NWG)
          v = __hip_atomic_load(&flags[lane * 8], __ATOMIC_RELAXED,
                                __HIP_MEMORY_SCOPE_AGENT);
        if (__all(v >= 1u)) break;
        __builtin_amdgcn_s_sleep(1);
      }
    }
    __syncthreads();
    asm volatile("" ::: "memory");
  }

  // epilogue mapping: em = (lane&31)+32*(wv&1) (row), 4 cols at c0
  const int em   = (lane & 31) + 32 * (wv & 1);
  const int c0   = ((wv >> 1) * 2 + (lane >> 5)) * 4;
  const int kcol = n0g + c0;
  const int kb_g = kcol >> 4;                 // global kb plane (2g or 2g+1)
  const int kq   = (c0 >> 3) & 1;
  const int lslot = kq * 32 + (em & 31);
  const size_t slotOff =
      ((((size_t)(wv & 1) * 64 + kb_g) * 64) + lslot) * 8 + (c0 & 7);
  float bias[4];
#pragma unroll
  for (int j = 0; j < 4; ++j) bias[j] = b_h[kcol + j];

  // this wave's 8 producer wgs: flags[(8ki+0..7)*8] (lane j<8 watches one)
  const int pflag = (8 * ki + (lane & 7)) * 8;

  // prefetch step-0 token + embedding row
  int tok_n = x[em * Sz];
  float4 xv_n = *(const float4*)&W_xh[(size_t)tok_n * Hz + kcol];

  int rp = 0;                               // read generation = s % 3
  for (int s = 0; s < Sz; ++s) {
    const int wp = (rp == 2) ? 0 : rp + 1;  // write generation
    const unsigned tgt = (unsigned)(s + 1); // producers' step-s data flag

    // fine-grained parallel WAIT on this wave's 8 producers (R13-proven)
    {
      for (int it = 0; it < 65536; ++it) {
        unsigned v = 0xFFFFFFFFu;
        if (lane < 8)
          v = __hip_atomic_load(&flags[pflag], __ATOMIC_RELAXED,
                                __HIP_MEMORY_SCOPE_AGENT);
        if (__all(v >= tgt)) break;
        __builtin_amdgcn_s_sleep(1);
      }
      asm volatile("" ::: "memory");
    }

    // issue all 16 A-fragment loads (no drain), consume pairwise with
    // descending vmcnt gates; MFMA order kst=0..15 (unchanged arithmetic).
    u32x4 t[16];
    load16_nodrain(&g_hfrag[rp][mi][ki * 16][lane][0], t);
    f32x16 acc = {};

#define STAGE(J, CNT)                                                          \
    {                                                                          \
      asm volatile("s_waitcnt vmcnt(" #CNT ")"                                 \
                   : "+v"(t[2 * (J)]), "+v"(t[2 * (J) + 1]));                  \
      int kb8a = ki * 32 + 4 * (J) + (lane >> 5);                              \
      short8 ba = *(const short8*)&ldsW[(size_t)(kb8a * 32 + bn) * 8];         \
      short8 bb = *(const short8*)&ldsW[(size_t)((kb8a + 2) * 32 + bn) * 8];   \
      acc = __builtin_amdgcn_mfma_f32_32x32x16_bf16(*(short8*)&t[2 * (J)],     \
                                                    ba, acc, 0, 0, 0);         \
      acc = __builtin_amdgcn_mfma_f32_32x32x16_bf16(*(short8*)&t[2 * (J) + 1], \
                                                    bb, acc, 0, 0, 0);         \
    }
    STAGE(0, 14) STAGE(1, 12) STAGE(2, 10) STAGE(3, 8)
    STAGE(4, 6)  STAGE(5, 4)  STAGE(6, 2)  STAGE(7, 0)
#undef STAGE

    // prefetch NEXT step's token + embedding row (hides gather latency)
    float4 xv = xv_n;
    if (s + 1 < Sz) {
      int t2 = x[em * Sz + s + 1];
      xv_n = *(const float4*)&W_xh[(size_t)t2 * Hz + kcol];
    }

    // single-sync 4-region K-split reduction (XOR-swizzled, <=2-way banks)
    // C/D: col=lane&31, row=(reg&3)+8*(reg>>2)+4*(lane>>5)  [m74/m101]
    {
      const int crow = 4 * (lane >> 5);
      float* reg = &red[ki * 2048];
#pragma unroll
      for (int r = 0; r < 16; ++r) {
        int m = mi * 32 + crow + (r & 3) + 8 * (r >> 2);
        reg[m * 32 + (bn ^ (m & 31))] = acc[r];
      }
    }
    __syncthreads();

    // epilogue: z = sum of 4 partials + emb + bias; h = tanh(z)
    float z[4];
    {
      const int sw = em & 31;
      const int base = em * 32;
#pragma unroll
      for (int j = 0; j < 4; ++j) {
        int off = base + ((c0 + j) ^ sw);
        z[j] = (red[off] + red[2048 + off]) + (red[4096 + off] + red[6144 + off]);
      }
    }
    z[0] = fast_tanh(z[0] + xv.x + bias[0]);
    z[1] = fast_tanh(z[1] + xv.y + bias[1]);
    z[2] = fast_tanh(z[2] + xv.z + bias[2]);
    z[3] = fast_tanh(z[3] + xv.w + bias[3]);

    u32x2 w2;
    w2.x = (unsigned)f2bf(z[0]) | ((unsigned)f2bf(z[1]) << 16);
    w2.y = (unsigned)f2bf(z[2]) | ((unsigned)f2bf(z[3]) << 16);

    // h store: fragment layout, wave-coalesced, write-through to L3
    store8_sc1(&((unsigned short*)g_hfrag)[(size_t)wp * 65536 + slotOff], w2);

    if (s == Sz - 1) {
      *(u32x2*)&g_hidden[(size_t)s * 65536 + slotOff] = w2;
      float* hf = out + (size_t)Bz * Sz * Vz + (size_t)em * Hz + kcol;
      float4 f0 = {z[0], z[1], z[2], z[3]};
      *(float4*)hf = f0;
    } else {
      // arrival (R8-proven): syncthreads drains all waves' h stores, then
      // tid0 publishes the wg flag. Consumer waits happen at next loop top.
      __syncthreads();
      if (tid == 0)
        __hip_atomic_store(&flags[g * 8], (unsigned)(s + 2), __ATOMIC_RELAXED,
                           __HIP_MEMORY_SCOPE_AGENT);
      // overlapped with flag propagation:
      *(u32x2*)&g_hidden[(size_t)s * 65536 + slotOff] = w2;
      asm volatile("" ::: "memory");
    }
    rp = wp;
  }
}

// ---------------- Phase 2: logits = hidden @ W_out + b_out -------------------
// grid: 1024 blocks = (s, mi); 4 waves; wave nt computes 32 rows x 32 cols, K=1024
__global__ __launch_bounds__(256) void logits_gemm(
    const float* __restrict__ b_out, float* __restrict__ out)
{
  const int tid = threadIdx.x, lane = tid & 63, nt = tid >> 6;
  const int s = blockIdx.x >> 1, mi = blockIdx.x & 1;
  const unsigned short* ab = &g_hidden[((size_t)s * 8192 + (size_t)mi * 4096) * 8];

  f32x16 acc = {};
#pragma unroll 8
  for (int kb = 0; kb < 64; ++kb) {
    short8 a = *(const short8*)&ab[(size_t)(kb * 64 + lane) * 8];
    short8 b = *(const short8*)&g_wout[(size_t)((kb * 4 + nt) * 64 + lane) * 8];
    acc = __builtin_amdgcn_mfma_f32_32x32x16_bf16(a, b, acc, 0, 0, 0);
  }
  const int col = nt * 32 + (lane & 31);
  const float bo = b_out[col];
  const int rbase = 4 * (lane >> 5);
#pragma unroll
  for (int r = 0; r < 16; ++r) {
    int m = rbase + (r & 3) + 8 * (r >> 2);
    int em = mi * 32 + m;
    out[((size_t)em * Sz + s) * Vz + col] = acc[r] + bo;
  }
}

// ---------------- host launcher ----------------------------------------------
extern "C" void kernel_launch(void* const* d_in, const int* in_sizes, int n_in,
                              void* d_out, int out_size, void* d_ws, size_t ws_size,
                              hipStream_t stream) {
  const int*   x     = (const int*)d_in[0];
  const float* h0    = (const float*)d_in[1];
  const float* W_xh  = (const float*)d_in[2];
  const float* W_hh  = (const float*)d_in[3];
  const float* b_h   = (const float*)d_in[4];
  const float* W_out = (const float*)d_in[5];
  const float* b_out = (const float*)d_in[6];
  float* out = (float*)d_out;

  (void)hipMemsetAsync(d_ws, 0, 1024, stream);    // 32 wg-flag lines (32 B each)
  pack_wout<<<64, 256, 0, stream>>>(W_out);
  rnn_persistent<<<NWG, WGT, 0, stream>>>(x, h0, W_xh, W_hh, b_h, out,
                                          (unsigned*)d_ws);
  logits_gemm<<<Sz * 2, 256, 0, stream>>>(b_out, out);
}